// Round 4
// baseline (335.390 us; speedup 1.0000x reference)
//
#include <hip/hip_runtime.h>
#include <math.h>

#define DIM 8388608
#define NBLK_RED 1024
#define EPS_F 1e-10f

typedef _Float16 h2 __attribute__((ext_vector_type(2)));

// ws layout (floats):
// [0 .. 4096)    per-block reduction partials: float4 per block {sum g^2, sum d^2, sum g*d, max|g|}
// [4096..4101)   s0, s1, s2, s3 (coeff_k * inv_norm), isq = 1/sqrt(1+it)
// [4104..5065)   h2 (w,w) conv weights/biases:
//                W0[80] B0[20] W1[400] B1[20] W2[400] B2[20] W3[20] B3[1]
#define WS_SCAL 4096
#define WS_WH   4104

__global__ __launch_bounds__(256) void reduce_k(const float4* __restrict__ g4,
                                                const float4* __restrict__ a4,
                                                const float4* __restrict__ b4,
                                                float4* __restrict__ part4) {
    const int N4 = DIM / 4;
    int tid = blockIdx.x * blockDim.x + threadIdx.x;
    int stride = gridDim.x * blockDim.x;
    float ssg = 0.f, ssd = 0.f, sgd = 0.f, mx = 0.f;
    for (int i = tid; i < N4; i += stride) {
        float4 gv = g4[i], av = a4[i], bv = b4[i];
        float d0 = bv.x - av.x, d1 = bv.y - av.y, d2 = bv.z - av.z, d3 = bv.w - av.w;
        ssg = fmaf(gv.x, gv.x, ssg); ssg = fmaf(gv.y, gv.y, ssg);
        ssg = fmaf(gv.z, gv.z, ssg); ssg = fmaf(gv.w, gv.w, ssg);
        ssd = fmaf(d0, d0, ssd); ssd = fmaf(d1, d1, ssd);
        ssd = fmaf(d2, d2, ssd); ssd = fmaf(d3, d3, ssd);
        sgd = fmaf(gv.x, d0, sgd); sgd = fmaf(gv.y, d1, sgd);
        sgd = fmaf(gv.z, d2, sgd); sgd = fmaf(gv.w, d3, sgd);
        mx = fmaxf(mx, fabsf(gv.x)); mx = fmaxf(mx, fabsf(gv.y));
        mx = fmaxf(mx, fabsf(gv.z)); mx = fmaxf(mx, fabsf(gv.w));
    }
    #pragma unroll
    for (int off = 32; off > 0; off >>= 1) {
        ssg += __shfl_down(ssg, off);
        ssd += __shfl_down(ssd, off);
        sgd += __shfl_down(sgd, off);
        mx = fmaxf(mx, __shfl_down(mx, off));
    }
    __shared__ float sm[4][4];
    int lane = threadIdx.x & 63, wid = threadIdx.x >> 6;
    if (lane == 0) { sm[wid][0] = ssg; sm[wid][1] = ssd; sm[wid][2] = sgd; sm[wid][3] = mx; }
    __syncthreads();
    if (threadIdx.x == 0) {
        float t0 = 0.f, t1 = 0.f, t2 = 0.f, t3 = 0.f;
        #pragma unroll
        for (int w = 0; w < 4; ++w) {
            t0 += sm[w][0]; t1 += sm[w][1]; t2 += sm[w][2]; t3 = fmaxf(t3, sm[w][3]);
        }
        part4[blockIdx.x] = make_float4(t0, t1, t2, t3);
    }
}

__global__ __launch_bounds__(64) void mlp_k(float* __restrict__ wsf,
                                            const float* __restrict__ loss_cur,
                                            const float* __restrict__ loss_old,
                                            const int* __restrict__ iter,
                                            const float* __restrict__ lw0, const float* __restrict__ lb0,
                                            const float* __restrict__ lw1, const float* __restrict__ lb1,
                                            const float* __restrict__ lw2, const float* __restrict__ lb2,
                                            const float* __restrict__ lw3, const float* __restrict__ lb3,
                                            const float* __restrict__ cw0, const float* __restrict__ cb0,
                                            const float* __restrict__ cw1, const float* __restrict__ cb1,
                                            const float* __restrict__ cw2, const float* __restrict__ cb2,
                                            const float* __restrict__ cw3, const float* __restrict__ cb3) {
    int t = threadIdx.x;

    // --- convert conv weights to (w,w) packed-half pairs in ws ---
    h2* wh = (h2*)(wsf + WS_WH);
    for (int i = t; i < 80;  i += 64) { _Float16 w = (_Float16)cw0[i]; wh[i]       = (h2){w, w}; }
    for (int i = t; i < 20;  i += 64) { _Float16 w = (_Float16)cb0[i]; wh[80 + i]  = (h2){w, w}; }
    for (int i = t; i < 400; i += 64) { _Float16 w = (_Float16)cw1[i]; wh[100 + i] = (h2){w, w}; }
    for (int i = t; i < 20;  i += 64) { _Float16 w = (_Float16)cb1[i]; wh[500 + i] = (h2){w, w}; }
    for (int i = t; i < 400; i += 64) { _Float16 w = (_Float16)cw2[i]; wh[520 + i] = (h2){w, w}; }
    for (int i = t; i < 20;  i += 64) { _Float16 w = (_Float16)cb2[i]; wh[920 + i] = (h2){w, w}; }
    for (int i = t; i < 20;  i += 64) { _Float16 w = (_Float16)cw3[i]; wh[940 + i] = (h2){w, w}; }
    if (t == 0) { _Float16 w = (_Float16)cb3[0]; wh[960] = (h2){w, w}; }

    // --- final reduction over per-block partials ---
    const float4* part4 = (const float4*)wsf;
    float ssg = 0.f, ssd = 0.f, sgd = 0.f, mx = 0.f;
    for (int b = t; b < NBLK_RED; b += 64) {
        float4 p = part4[b];
        ssg += p.x; ssd += p.y; sgd += p.z; mx = fmaxf(mx, p.w);
    }
    #pragma unroll
    for (int off = 32; off > 0; off >>= 1) {
        ssg += __shfl_down(ssg, off);
        ssd += __shfl_down(ssd, off);
        sgd += __shfl_down(sgd, off);
        mx = fmaxf(mx, __shfl_down(mx, off));
    }
    __shared__ float red[4];
    if (t == 0) { red[0] = ssg; red[1] = ssd; red[2] = sgd; red[3] = mx; }
    __syncthreads();

    __shared__ float buf[32];
    __shared__ float nxt[32];
    float gn = sqrtf(red[0]);
    float dn = sqrtf(red[1]);
    float inv_gn = (gn > EPS_F) ? 1.f / gn : 1.f;
    float inv_dn = (dn > EPS_F) ? 1.f / dn : 1.f;
    float it = (float)iter[0];
    if (t < 6) {
        float f = 0.f;
        if (t == 0) f = log1pf(gn);
        else if (t == 1) f = log1pf(dn);
        else if (t == 2) f = red[2] * inv_gn * inv_dn;
        else if (t == 3) f = red[3] * inv_gn;
        else if (t == 4) f = it;
        else f = logf(loss_cur[0]) - logf(loss_old[0]);
        buf[t] = f;
    }
    __syncthreads();
    float acc;
    if (t < 30) {
        acc = lb0[t];
        #pragma unroll
        for (int c = 0; c < 6; ++c) acc = fmaf(lw0[t * 6 + c], buf[c], acc);
        nxt[t] = fmaxf(acc, 0.f);
    }
    __syncthreads();
    if (t < 20) {
        acc = lb1[t];
        #pragma unroll
        for (int c = 0; c < 30; ++c) acc = fmaf(lw1[t * 30 + c], nxt[c], acc);
        buf[t] = fmaxf(acc, 0.f);
    }
    __syncthreads();
    if (t < 10) {
        acc = lb2[t];
        #pragma unroll
        for (int c = 0; c < 20; ++c) acc = fmaf(lw2[t * 20 + c], buf[c], acc);
        nxt[t] = fmaxf(acc, 0.f);
    }
    __syncthreads();
    if (t < 4) {
        acc = lb3[t];
        #pragma unroll
        for (int c = 0; c < 10; ++c) acc = fmaf(lw3[t * 10 + c], nxt[c], acc);
        float s = ((t & 1) == 0) ? acc * inv_gn : acc * inv_dn;  // t=0,2 g-path; t=1,3 d-path
        wsf[WS_SCAL + t] = s;
    }
    if (t == 0) wsf[WS_SCAL + 4] = rsqrtf(1.f + it);
}

// 2 elements per thread: one packed-f16 lane-pair. Live activations = h[20]+hb[20]
// = 40 VGPRs -> no spill (R3's 4-elem version needed 80 live in 44 allocated).
__global__ __launch_bounds__(256) void apply_k(const float2* __restrict__ g2,
                                               const float2* __restrict__ a2,
                                               const float2* __restrict__ b2,
                                               const float2* __restrict__ gp2,
                                               const float2* __restrict__ ex2,
                                               const float* __restrict__ wsf,
                                               float2* __restrict__ out2) {
    // uniform scalars (scalar loads)
    float s0 = wsf[WS_SCAL + 0], s1 = wsf[WS_SCAL + 1];
    float s2 = wsf[WS_SCAL + 2], s3 = wsf[WS_SCAL + 3];
    float isq = wsf[WS_SCAL + 4];
    const h2* __restrict__ wh = (const h2*)(wsf + WS_WH);
    const h2* W0 = wh;        const h2* B0 = wh + 80;
    const h2* W1 = wh + 100;  const h2* B1 = wh + 500;
    const h2* W2 = wh + 520;  const h2* B2 = wh + 920;
    const h2* W3 = wh + 940;  const h2  B3v = wh[960];

    int i = blockIdx.x * blockDim.x + threadIdx.x;   // exactly DIM/2 threads
    float2 gv = g2[i], av = a2[i], bv = b2[i], pv = gp2[i], ev = ex2[i];
    float de0 = bv.x - av.x, de1 = bv.y - av.y;

    h2 xh[4];
    xh[0] = (h2){(_Float16)(s0 * pv.x * gv.x), (_Float16)(s0 * pv.y * gv.y)};
    xh[1] = (h2){(_Float16)(s1 * ev.x * de0), (_Float16)(s1 * ev.y * de1)};
    xh[2] = (h2){(_Float16)(s2 * gv.x), (_Float16)(s2 * gv.y)};
    xh[3] = (h2){(_Float16)(s3 * de0), (_Float16)(s3 * de1)};

    const h2 zero = (h2){(_Float16)0.f, (_Float16)0.f};
    h2 h[20], hb[20];
    // layer0: 4 -> 20, relu
    #pragma unroll
    for (int o = 0; o < 20; ++o) {
        h2 c0 = B0[o];
        #pragma unroll
        for (int c = 0; c < 4; ++c)
            c0 = __builtin_elementwise_fma(W0[o * 4 + c], xh[c], c0);
        h[o] = __builtin_elementwise_max(c0, zero);
    }
    // layer1: 20 -> 20, relu
    #pragma unroll
    for (int o = 0; o < 20; ++o) {
        h2 c0 = B1[o];
        #pragma unroll
        for (int c = 0; c < 20; ++c)
            c0 = __builtin_elementwise_fma(W1[o * 20 + c], h[c], c0);
        hb[o] = __builtin_elementwise_max(c0, zero);
    }
    // layer2: 20 -> 20, relu
    #pragma unroll
    for (int o = 0; o < 20; ++o) {
        h2 c0 = B2[o];
        #pragma unroll
        for (int c = 0; c < 20; ++c)
            c0 = __builtin_elementwise_fma(W2[o * 20 + c], hb[c], c0);
        h[o] = __builtin_elementwise_max(c0, zero);
    }
    // layer3: 20 -> 1 (no relu)
    h2 d0 = B3v;
    #pragma unroll
    for (int c = 0; c < 20; ++c)
        d0 = __builtin_elementwise_fma(W3[c], h[c], d0);

    float2 outv;
    outv.x = fmaf((float)d0[0], isq, bv.x);
    outv.y = fmaf((float)d0[1], isq, bv.y);
    out2[i] = outv;
}

extern "C" void kernel_launch(void* const* d_in, const int* in_sizes, int n_in,
                              void* d_out, int out_size, void* d_ws, size_t ws_size,
                              hipStream_t stream) {
    const float* grad    = (const float*)d_in[0];
    const float* state0  = (const float*)d_in[1];
    const float* state1  = (const float*)d_in[2];
    const float* losscur = (const float*)d_in[3];
    const float* lossold = (const float*)d_in[4];
    const int*   iter    = (const int*)d_in[5];
    const float* gparam  = (const float*)d_in[6];
    const float* extrap  = (const float*)d_in[7];
    const float* cw0 = (const float*)d_in[8];  const float* cb0 = (const float*)d_in[9];
    const float* cw1 = (const float*)d_in[10]; const float* cb1 = (const float*)d_in[11];
    const float* cw2 = (const float*)d_in[12]; const float* cb2 = (const float*)d_in[13];
    const float* cw3 = (const float*)d_in[14]; const float* cb3 = (const float*)d_in[15];
    const float* lw0 = (const float*)d_in[16]; const float* lb0 = (const float*)d_in[17];
    const float* lw1 = (const float*)d_in[18]; const float* lb1 = (const float*)d_in[19];
    const float* lw2 = (const float*)d_in[20]; const float* lb2 = (const float*)d_in[21];
    const float* lw3 = (const float*)d_in[22]; const float* lb3 = (const float*)d_in[23];

    float* wsf = (float*)d_ws;
    float* out = (float*)d_out;

    reduce_k<<<NBLK_RED, 256, 0, stream>>>((const float4*)grad, (const float4*)state0,
                                           (const float4*)state1, (float4*)wsf);

    mlp_k<<<1, 64, 0, stream>>>(wsf, losscur, lossold, iter,
                                lw0, lb0, lw1, lb1, lw2, lb2, lw3, lb3,
                                cw0, cb0, cw1, cb1, cw2, cb2, cw3, cb3);

    apply_k<<<DIM / 2 / 256, 256, 0, stream>>>((const float2*)grad, (const float2*)state0,
                                               (const float2*)state1, (const float2*)gparam,
                                               (const float2*)extrap,
                                               wsf, (float2*)out);
}